// Round 10
// baseline (168.684 us; speedup 1.0000x reference)
//
#include <hip/hip_runtime.h>

#define D_DIRS 1296
#define K_PTS  64
#define R_RANK 16
#define F_SUB  408
#define DT_VAL (200.0f / 64.0f)

#define NBLOCKS (D_DIRS / 2)                 // 648 blocks, 2 dirs sequential
#define PARTIAL_FLOATS 8704                  // 8192 T + 512 G per slab
#define RED_CHUNKS 12
#define SLABS_PER_CHUNK (NBLOCKS / RED_CHUNKS)   // 54
#define NEED_BYTES ((size_t)(RED_CHUNKS + NBLOCKS) * PARTIAL_FLOATS * 4)
#define SKEW(e) ((e) + ((e) >> 5))

// ---------------------------------------------------------------------------
// accum: 2 directions sequentially per block. att staged interleaved as
// float4 {re,im,re,im} (aliased as float2 for the b-read), rad as float2.
// Reverse-cumsum formulation:
//   S(k) = sum_{k'>=max(k,1)} w(k'),  w = conj(rad)_i * conj(att)_j
//   T[i,j,l] = dt * sum_k att_l(k) * S(max(k,1));  G[i,j] = S(1) + w(0)
// Thread t owns (i = t>>4, j = t&15); 32 acc floats MUST live in arch VGPRs:
// __launch_bounds__(256,4) caps the reg class at 128 so the RA doesn't
// AGPR-shuffle them (rounds 8/9: VGPR_Count 36-40 => 3x VALU inflation).
// ---------------------------------------------------------------------------
template <bool USE_PARTIALS>
__global__ __launch_bounds__(256, 4) void accum_kernel_t(
    const float* __restrict__ att_r, const float* __restrict__ att_i,
    const float* __restrict__ rad_r, const float* __restrict__ rad_i,
    float* __restrict__ pbuf, float* __restrict__ atomic_dst)
{
    __shared__ float4 sAtt4[2][K_PTS * 8];        // 16 KB; aliases float2[64][16]
    __shared__ float2 sRad2[2][K_PTS * R_RANK];   // 16 KB

    const int t  = threadIdx.x;
    const int ri = t >> 4;
    const int rj = t & 15;

    // ---- stage both directions (coalesced b64 loads, interleave on the fly)
    for (int h = 0; h < 2; ++h) {
        const int base = (blockIdx.x * 2 + h) * K_PTS * R_RANK;
#pragma unroll
        for (int s = t; s < 512; s += 256) {
            float2 ar = *(const float2*)(att_r + base + 2 * s);
            float2 ai = *(const float2*)(att_i + base + 2 * s);
            sAtt4[h][s] = make_float4(ar.x, ai.x, ar.y, ai.y);
            float2 rr = *(const float2*)(rad_r + base + 2 * s);
            float2 rim = *(const float2*)(rad_i + base + 2 * s);
            sRad2[h][2 * s]     = make_float2(rr.x, rim.x);
            sRad2[h][2 * s + 1] = make_float2(rr.y, rim.y);
        }
    }
    __syncthreads();

    float accR[16], accI[16];
#pragma unroll
    for (int l = 0; l < 16; ++l) { accR[l] = 0.f; accI[l] = 0.f; }
    float gR = 0.f, gI = 0.f;

    for (int h = 0; h < 2; ++h) {
        const float2* rad2 = sRad2[h];
        const float2* att2 = (const float2*)sAtt4[h];
        const float4* att4 = sAtt4[h];

        float Sr = 0.f, Si = 0.f;
        for (int k = K_PTS - 1; k >= 1; --k) {
            float2 a = rad2[k * 16 + ri];
            float2 b = att2[k * 16 + rj];
            Sr += a.x * b.x - a.y * b.y;      // S += conj(rad)_i*conj(att)_j
            Si -= a.x * b.y + a.y * b.x;
#pragma unroll
            for (int q = 0; q < 8; ++q) {
                float4 c = att4[k * 8 + q];   // broadcast read, complex 2q,2q+1
                accR[2 * q]     += Sr * c.x - Si * c.y;
                accI[2 * q]     += Sr * c.y + Si * c.x;
                accR[2 * q + 1] += Sr * c.z - Si * c.w;
                accI[2 * q + 1] += Sr * c.w + Si * c.z;
            }
        }
        // k = 0: T-term uses S(1) (current S); G = S(1) + w(0)
#pragma unroll
        for (int q = 0; q < 8; ++q) {
            float4 c = att4[q];
            accR[2 * q]     += Sr * c.x - Si * c.y;
            accI[2 * q]     += Sr * c.y + Si * c.x;
            accR[2 * q + 1] += Sr * c.z - Si * c.w;
            accI[2 * q + 1] += Sr * c.w + Si * c.z;
        }
        float2 a0 = rad2[ri], b0 = att2[rj];
        gR += Sr + (a0.x * b0.x - a0.y * b0.y);
        gI += Si - (a0.x * b0.y + a0.y * b0.x);
    }

    // ---- emit (dt applied here; layout e = ((i*16+j)*16 + l)*2 + c)
    if (USE_PARTIALS) {
        float4* slabT = (float4*)(pbuf + (size_t)blockIdx.x * PARTIAL_FLOATS);
#pragma unroll
        for (int v = 0; v < 8; ++v) {
            slabT[t * 8 + v] = make_float4(
                accR[2 * v] * DT_VAL,     accI[2 * v] * DT_VAL,
                accR[2 * v + 1] * DT_VAL, accI[2 * v + 1] * DT_VAL);
        }
        float2* slabG = (float2*)(pbuf + (size_t)blockIdx.x * PARTIAL_FLOATS + 8192);
        slabG[t] = make_float2(gR, gI);
    } else {
#pragma unroll
        for (int l = 0; l < 16; ++l) {
            atomicAdd(&atomic_dst[(t * 16 + l) * 2 + 0], accR[l] * DT_VAL);
            atomicAdd(&atomic_dst[(t * 16 + l) * 2 + 1], accI[l] * DT_VAL);
        }
        atomicAdd(&atomic_dst[8192 + t * 2 + 0], gR);
        atomicAdd(&atomic_dst[8192 + t * 2 + 1], gI);
    }
}

// ---------------------------------------------------------------------------
// reduce1: chunk c (blockIdx.y) sums its 54 slabs elementwise into red1[c].
// ---------------------------------------------------------------------------
__global__ __launch_bounds__(256) void reduce1_kernel(
    const float* __restrict__ pbuf, float* __restrict__ red1)
{
    int e = blockIdx.x * 256 + threadIdx.x;              // 34*256 == 8704
    const float* p = pbuf + (size_t)blockIdx.y * SLABS_PER_CHUNK * PARTIAL_FLOATS + e;
    float s = 0.f;
#pragma unroll 6
    for (int b = 0; b < SLABS_PER_CHUNK; ++b)
        s += p[(size_t)b * PARTIAL_FLOATS];
    red1[blockIdx.y * PARTIAL_FLOATS + e] = s;
}

// ---------------------------------------------------------------------------
// contract (fused final reduce): stage TG = sum_{c<12} red1[c] into skewed
// LDS (coalesced global reads; skew kills the stride-32 bank conflict on the
// strided T reads), then csi[f] = (dt/D) * sum_{ij}(G + sum_l T f_l) f_i f_j.
// OUTPUT: float32 PLANAR — out[f] = re, out[F_SUB+f] = im.
// ---------------------------------------------------------------------------
__global__ __launch_bounds__(256) void contract_kernel(
    const float* __restrict__ fr, const float* __restrict__ fi,
    const float* __restrict__ red1, float* __restrict__ out)
{
    __shared__ float sTG[PARTIAL_FLOATS + PARTIAL_FLOATS / 32];  // skewed
    __shared__ float sfr[16], sfi[16];

    const int f = blockIdx.x;
    const int t = threadIdx.x;

    for (int e = t; e < PARTIAL_FLOATS; e += 256) {
        float s = 0.f;
#pragma unroll
        for (int c = 0; c < RED_CHUNKS; ++c)
            s += red1[c * PARTIAL_FLOATS + e];
        sTG[SKEW(e)] = s;
    }
    if (t < 16) {
        sfr[t] = fr[f * R_RANK + t];
        sfi[t] = fi[f * R_RANK + t];
    }
    __syncthreads();

    const int i = t >> 4, j = t & 15;
    float fir = sfr[i], fii = sfi[i];
    float fjr = sfr[j], fji = sfi[j];
    float mr = fir * fjr - fii * fji;   // f_i * f_j
    float mi = fir * fji + fii * fjr;

    int gbase = 8192 + t * 2;
    float Sr = sTG[SKEW(gbase)];
    float Si = sTG[SKEW(gbase + 1)];
#pragma unroll
    for (int l = 0; l < 16; ++l) {
        int e0 = (t * 16 + l) * 2;
        float Tr = sTG[SKEW(e0)];
        float Ti = sTG[SKEW(e0 + 1)];
        float flr = sfr[l], fli = sfi[l];
        Sr += Tr * flr - Ti * fli;
        Si += Tr * fli + Ti * flr;
    }

    float vr = Sr * mr - Si * mi;
    float vi = Sr * mi + Si * mr;

#pragma unroll
    for (int off = 32; off >= 1; off >>= 1) {
        vr += __shfl_down(vr, off, 64);
        vi += __shfl_down(vi, off, 64);
    }
    __shared__ float red[8];
    const int lane = t & 63, w = t >> 6;
    if (lane == 0) { red[w * 2] = vr; red[w * 2 + 1] = vi; }
    __syncthreads();
    if (t == 0) {
        float rr = red[0] + red[2] + red[4] + red[6];
        float ii = red[1] + red[3] + red[5] + red[7];
        const float scale = DT_VAL / (float)D_DIRS;
        out[f]         = rr * scale;
        out[F_SUB + f] = ii * scale;
    }
}

// ---------------------------------------------------------------------------
extern "C" void kernel_launch(void* const* d_in, const int* in_sizes, int n_in,
                              void* d_out, int out_size, void* d_ws, size_t ws_size,
                              hipStream_t stream)
{
    const float* att_r = (const float*)d_in[0];
    const float* att_i = (const float*)d_in[1];
    const float* rad_r = (const float*)d_in[2];
    const float* rad_i = (const float*)d_in[3];
    const float* fr    = (const float*)d_in[4];
    const float* fi    = (const float*)d_in[5];

    float* ws   = (float*)d_ws;
    float* red1 = ws;                                   // 12 * 8704 floats
    float* pbuf = ws + RED_CHUNKS * PARTIAL_FLOATS;     // 648 * 8704 floats

    const bool use_partials = ws_size >= NEED_BYTES;

    if (use_partials) {
        accum_kernel_t<true><<<NBLOCKS, 256, 0, stream>>>(
            att_r, att_i, rad_r, rad_i, pbuf, red1);
        reduce1_kernel<<<dim3(PARTIAL_FLOATS / 256, RED_CHUNKS), 256, 0, stream>>>(
            pbuf, red1);
    } else {
        // fallback: atomics into red1 chunk 0; zero all chunks first
        hipMemsetAsync(red1, 0, RED_CHUNKS * PARTIAL_FLOATS * sizeof(float), stream);
        accum_kernel_t<false><<<NBLOCKS, 256, 0, stream>>>(
            att_r, att_i, rad_r, rad_i, pbuf, red1);
    }

    contract_kernel<<<F_SUB, 256, 0, stream>>>(
        fr, fi, red1, (float*)d_out);
}

// Round 11
// 168.439 us; speedup vs baseline: 1.0015x; 1.0015x over previous
//
#include <hip/hip_runtime.h>

#define D_DIRS 1296
#define K_PTS  64
#define R_RANK 16
#define F_SUB  408
#define DT_VAL (200.0f / 64.0f)

#define NBLOCKS (D_DIRS / 2)                 // 648 blocks, 2 dirs in parallel halves
#define PARTIAL_FLOATS 8704                  // 8192 T + 512 G per slab
#define RED_CHUNKS 12
#define SLABS_PER_CHUNK (NBLOCKS / RED_CHUNKS)   // 54
#define NEED_BYTES ((size_t)(RED_CHUNKS + NBLOCKS) * PARTIAL_FLOATS * 4)
#define SKEW(e) ((e) + ((e) >> 5))

// ---------------------------------------------------------------------------
// accum: 256 threads = 2 halves; half h owns direction d = 2*blk + h.
// Thread t2 (in-half) owns TWO ij pairs: (i0 = t2>>4, j) and (i1 = i0+8, j)
// -> the 8 broadcast float4 att-reads per k feed 128 FMAs (2x intensity).
// Reverse-cumsum: S(k) = sum_{k'>=max(k,1)} conj(rad)_i*conj(att)_j
//   T[i,j,l] = dt * sum_k att_l(k)*S(max(k,1));  G[i,j] = S(1) + w(0)
// Cross-half merge via LDS (slot-rotated b128 writes), then h=0 emits slab.
// ---------------------------------------------------------------------------
union SMem {
    struct {
        float4 att4[2][K_PTS * 8];           // [h][k*8+q] = complex 2q,2q+1
        float2 rad2[2][K_PTS * R_RANK];      // [h][k*16+i]
    } tiles;                                  // 32 KB
    float4 mrgT[2048];                        // 32 KB merge region (reused)
};

template <bool USE_PARTIALS>
__global__ __launch_bounds__(256, 2) void accum_kernel_t(
    const float* __restrict__ att_r, const float* __restrict__ att_i,
    const float* __restrict__ rad_r, const float* __restrict__ rad_i,
    float* __restrict__ pbuf, float* __restrict__ atomic_dst)
{
    __shared__ SMem sm;

    const int t  = threadIdx.x;
    const int h  = t >> 7;           // direction half: 0 or 1
    const int t2 = t & 127;
    const int i0 = t2 >> 4;          // 0..7
    const int i1 = i0 + 8;           // 8..15
    const int j  = t2 & 15;

    // ---- stage both directions (coalesced b64 loads, interleave on the fly)
    for (int hh = 0; hh < 2; ++hh) {
        const int base = (blockIdx.x * 2 + hh) * (K_PTS * R_RANK);
#pragma unroll
        for (int s = t; s < 512; s += 256) {
            float2 ar = *(const float2*)(att_r + base + 2 * s);
            float2 ai = *(const float2*)(att_i + base + 2 * s);
            sm.tiles.att4[hh][s] = make_float4(ar.x, ai.x, ar.y, ai.y);
            float2 rr = *(const float2*)(rad_r + base + 2 * s);
            float2 rm = *(const float2*)(rad_i + base + 2 * s);
            sm.tiles.rad2[hh][2 * s]     = make_float2(rr.x, rm.x);
            sm.tiles.rad2[hh][2 * s + 1] = make_float2(rr.y, rm.y);
        }
    }
    __syncthreads();

    const float4* att4 = sm.tiles.att4[h];
    const float2* att2 = (const float2*)att4;
    const float2* rad2 = sm.tiles.rad2[h];

    float aR0[16], aI0[16], aR1[16], aI1[16];
#pragma unroll
    for (int l = 0; l < 16; ++l) { aR0[l] = aI0[l] = aR1[l] = aI1[l] = 0.f; }
    float S0r = 0.f, S0i = 0.f, S1r = 0.f, S1i = 0.f;

    for (int k = K_PTS - 1; k >= 1; --k) {
        float2 a0 = rad2[k * 16 + i0];
        float2 a1 = rad2[k * 16 + i1];
        float2 b  = att2[k * 16 + j];
        S0r += a0.x * b.x - a0.y * b.y;   S0i -= a0.x * b.y + a0.y * b.x;
        S1r += a1.x * b.x - a1.y * b.y;   S1i -= a1.x * b.y + a1.y * b.x;
#pragma unroll
        for (int q = 0; q < 8; ++q) {
            float4 c = att4[k * 8 + q];            // broadcast read
            aR0[2*q]   += S0r * c.x - S0i * c.y;
            aI0[2*q]   += S0r * c.y + S0i * c.x;
            aR0[2*q+1] += S0r * c.z - S0i * c.w;
            aI0[2*q+1] += S0r * c.w + S0i * c.z;
            aR1[2*q]   += S1r * c.x - S1i * c.y;
            aI1[2*q]   += S1r * c.y + S1i * c.x;
            aR1[2*q+1] += S1r * c.z - S1i * c.w;
            aI1[2*q+1] += S1r * c.w + S1i * c.z;
        }
    }
    // k = 0: T-term uses current S (= S(1)); G = S(1) + w(0)
#pragma unroll
    for (int q = 0; q < 8; ++q) {
        float4 c = att4[q];
        aR0[2*q]   += S0r * c.x - S0i * c.y;
        aI0[2*q]   += S0r * c.y + S0i * c.x;
        aR0[2*q+1] += S0r * c.z - S0i * c.w;
        aI0[2*q+1] += S0r * c.w + S0i * c.z;
        aR1[2*q]   += S1r * c.x - S1i * c.y;
        aI1[2*q]   += S1r * c.y + S1i * c.x;
        aR1[2*q+1] += S1r * c.z - S1i * c.w;
        aI1[2*q+1] += S1r * c.w + S1i * c.z;
    }
    {
        float2 a0 = rad2[i0], a1 = rad2[i1], b0 = att2[j];
        S0r += a0.x * b0.x - a0.y * b0.y;   S0i -= a0.x * b0.y + a0.y * b0.x;
        S1r += a1.x * b0.x - a1.y * b0.y;   S1i -= a1.x * b0.y + a1.y * b0.x;
    }
    // now (S0r,S0i) = G[i0,j], (S1r,S1i) = G[i1,j] for this direction

    const int r0 = t2;               // i0*16 + j
    const int r1 = t2 + 128;         // i1*16 + j

    __syncthreads();                 // tiles dead; merge region live

    if (USE_PARTIALS) {
        if (h == 1) {
#pragma unroll
            for (int q = 0; q < 8; ++q) {
                sm.mrgT[r0 * 8 + ((q + r0) & 7)] =
                    make_float4(aR0[2*q], aI0[2*q], aR0[2*q+1], aI0[2*q+1]);
                sm.mrgT[r1 * 8 + ((q + r1) & 7)] =
                    make_float4(aR1[2*q], aI1[2*q], aR1[2*q+1], aI1[2*q+1]);
            }
        }
        __syncthreads();
        if (h == 0) {
            float4* slabT = (float4*)(pbuf + (size_t)blockIdx.x * PARTIAL_FLOATS);
#pragma unroll
            for (int q = 0; q < 8; ++q) {
                float4 o0 = sm.mrgT[r0 * 8 + ((q + r0) & 7)];
                slabT[r0 * 8 + q] = make_float4(
                    (aR0[2*q]   + o0.x) * DT_VAL, (aI0[2*q]   + o0.y) * DT_VAL,
                    (aR0[2*q+1] + o0.z) * DT_VAL, (aI0[2*q+1] + o0.w) * DT_VAL);
                float4 o1 = sm.mrgT[r1 * 8 + ((q + r1) & 7)];
                slabT[r1 * 8 + q] = make_float4(
                    (aR1[2*q]   + o1.x) * DT_VAL, (aI1[2*q]   + o1.y) * DT_VAL,
                    (aR1[2*q+1] + o1.z) * DT_VAL, (aI1[2*q+1] + o1.w) * DT_VAL);
            }
        }
        __syncthreads();
        float2* mrgG = (float2*)sm.mrgT;
        if (h == 1) {
            mrgG[r0] = make_float2(S0r, S0i);
            mrgG[r1] = make_float2(S1r, S1i);
        }
        __syncthreads();
        if (h == 0) {
            float2* slabG = (float2*)(pbuf + (size_t)blockIdx.x * PARTIAL_FLOATS + 8192);
            float2 o0 = mrgG[r0], o1 = mrgG[r1];
            slabG[r0] = make_float2(S0r + o0.x, S0i + o0.y);
            slabG[r1] = make_float2(S1r + o1.x, S1i + o1.y);
        }
    } else {
        // fallback: device atomics (dst pre-zeroed)
#pragma unroll
        for (int l = 0; l < 16; ++l) {
            atomicAdd(&atomic_dst[(r0 * 16 + l) * 2 + 0], aR0[l] * DT_VAL);
            atomicAdd(&atomic_dst[(r0 * 16 + l) * 2 + 1], aI0[l] * DT_VAL);
            atomicAdd(&atomic_dst[(r1 * 16 + l) * 2 + 0], aR1[l] * DT_VAL);
            atomicAdd(&atomic_dst[(r1 * 16 + l) * 2 + 1], aI1[l] * DT_VAL);
        }
        atomicAdd(&atomic_dst[8192 + r0 * 2 + 0], S0r);
        atomicAdd(&atomic_dst[8192 + r0 * 2 + 1], S0i);
        atomicAdd(&atomic_dst[8192 + r1 * 2 + 0], S1r);
        atomicAdd(&atomic_dst[8192 + r1 * 2 + 1], S1i);
    }
}

// ---------------------------------------------------------------------------
// reduce1: chunk c (blockIdx.y) sums its 54 slabs elementwise into red1[c].
// ---------------------------------------------------------------------------
__global__ __launch_bounds__(256) void reduce1_kernel(
    const float* __restrict__ pbuf, float* __restrict__ red1)
{
    int e = blockIdx.x * 256 + threadIdx.x;              // 34*256 == 8704
    const float* p = pbuf + (size_t)blockIdx.y * SLABS_PER_CHUNK * PARTIAL_FLOATS + e;
    float s = 0.f;
#pragma unroll 6
    for (int b = 0; b < SLABS_PER_CHUNK; ++b)
        s += p[(size_t)b * PARTIAL_FLOATS];
    red1[blockIdx.y * PARTIAL_FLOATS + e] = s;
}

// ---------------------------------------------------------------------------
// contract (fused final reduce): TG = sum_{c<12} red1[c] staged in skewed LDS,
// then csi[f] = (dt/D) * sum_{ij}(G + sum_l T f_l) f_i f_j.
// OUTPUT: float32 PLANAR — out[f] = re, out[F_SUB+f] = im.
// ---------------------------------------------------------------------------
__global__ __launch_bounds__(256) void contract_kernel(
    const float* __restrict__ fr, const float* __restrict__ fi,
    const float* __restrict__ red1, float* __restrict__ out)
{
    __shared__ float sTG[PARTIAL_FLOATS + PARTIAL_FLOATS / 32];  // skewed
    __shared__ float sfr[16], sfi[16];

    const int f = blockIdx.x;
    const int t = threadIdx.x;

    for (int e = t; e < PARTIAL_FLOATS; e += 256) {
        float s = 0.f;
#pragma unroll
        for (int c = 0; c < RED_CHUNKS; ++c)
            s += red1[c * PARTIAL_FLOATS + e];
        sTG[SKEW(e)] = s;
    }
    if (t < 16) {
        sfr[t] = fr[f * R_RANK + t];
        sfi[t] = fi[f * R_RANK + t];
    }
    __syncthreads();

    const int i = t >> 4, j = t & 15;
    float fir = sfr[i], fii = sfi[i];
    float fjr = sfr[j], fji = sfi[j];
    float mr = fir * fjr - fii * fji;   // f_i * f_j
    float mi = fir * fji + fii * fjr;

    int gbase = 8192 + t * 2;
    float Sr = sTG[SKEW(gbase)];
    float Si = sTG[SKEW(gbase + 1)];
#pragma unroll
    for (int l = 0; l < 16; ++l) {
        int e0 = (t * 16 + l) * 2;
        float Tr = sTG[SKEW(e0)];
        float Ti = sTG[SKEW(e0 + 1)];
        float flr = sfr[l], fli = sfi[l];
        Sr += Tr * flr - Ti * fli;
        Si += Tr * fli + Ti * flr;
    }

    float vr = Sr * mr - Si * mi;
    float vi = Sr * mi + Si * mr;

#pragma unroll
    for (int off = 32; off >= 1; off >>= 1) {
        vr += __shfl_down(vr, off, 64);
        vi += __shfl_down(vi, off, 64);
    }
    __shared__ float red[8];
    const int lane = t & 63, w = t >> 6;
    if (lane == 0) { red[w * 2] = vr; red[w * 2 + 1] = vi; }
    __syncthreads();
    if (t == 0) {
        float rr = red[0] + red[2] + red[4] + red[6];
        float ii = red[1] + red[3] + red[5] + red[7];
        const float scale = DT_VAL / (float)D_DIRS;
        out[f]         = rr * scale;
        out[F_SUB + f] = ii * scale;
    }
}

// ---------------------------------------------------------------------------
extern "C" void kernel_launch(void* const* d_in, const int* in_sizes, int n_in,
                              void* d_out, int out_size, void* d_ws, size_t ws_size,
                              hipStream_t stream)
{
    const float* att_r = (const float*)d_in[0];
    const float* att_i = (const float*)d_in[1];
    const float* rad_r = (const float*)d_in[2];
    const float* rad_i = (const float*)d_in[3];
    const float* fr    = (const float*)d_in[4];
    const float* fi    = (const float*)d_in[5];

    float* ws   = (float*)d_ws;
    float* red1 = ws;                                   // 12 * 8704 floats
    float* pbuf = ws + RED_CHUNKS * PARTIAL_FLOATS;     // 648 * 8704 floats

    const bool use_partials = ws_size >= NEED_BYTES;

    if (use_partials) {
        accum_kernel_t<true><<<NBLOCKS, 256, 0, stream>>>(
            att_r, att_i, rad_r, rad_i, pbuf, red1);
        reduce1_kernel<<<dim3(PARTIAL_FLOATS / 256, RED_CHUNKS), 256, 0, stream>>>(
            pbuf, red1);
    } else {
        // fallback: atomics into red1 chunk 0; zero all chunks first
        hipMemsetAsync(red1, 0, RED_CHUNKS * PARTIAL_FLOATS * sizeof(float), stream);
        accum_kernel_t<false><<<NBLOCKS, 256, 0, stream>>>(
            att_r, att_i, rad_r, rad_i, pbuf, red1);
    }

    contract_kernel<<<F_SUB, 256, 0, stream>>>(
        fr, fi, red1, (float*)d_out);
}